// Round 6
// baseline (279.236 us; speedup 1.0000x reference)
//
#include <hip/hip_runtime.h>
#include <hip/hip_bf16.h>
#include <math.h>

typedef __bf16 bf16;
typedef __bf16 bf16x2 __attribute__((ext_vector_type(2)));
typedef __bf16 bf16x4 __attribute__((ext_vector_type(4)));
typedef __bf16 bf16x8 __attribute__((ext_vector_type(8)));
typedef float  f32x4  __attribute__((ext_vector_type(4)));

#define NB 4
#define SS 8192
#define DD 1024
#define MM 32768
#define KK 1024
#define NN 1024
#define NTK 32            // K-steps of 32
#define PI_F 3.14159265358979323846f

__device__ __forceinline__ void gl2lds16(const bf16* g, bf16* l) {
    __builtin_amdgcn_global_load_lds(
        (const __attribute__((address_space(1))) void*)g,
        (__attribute__((address_space(3))) void*)l, 16, 0, 0);
}

// ---- fused prep: x->bf16 cast (blocks [0,MM)), W build + hm zero ----
__global__ __launch_bounds__(256) void prep_all(const float* __restrict__ x,
                                                bf16* __restrict__ xb,
                                                const float* __restrict__ W_proj,
                                                const float* __restrict__ freqs,
                                                const float* __restrict__ W_out,
                                                bf16* __restrict__ WbT1,
                                                bf16* __restrict__ WoT,
                                                float* __restrict__ hm) {
    int blk = blockIdx.x;
    if (blk < MM) {
        size_t i = (size_t)blk * 1024 + threadIdx.x * 4;
        float4 v = *(const float4*)&x[i];
        bf16x4 o;
        o[0] = (bf16)v.x; o[1] = (bf16)v.y; o[2] = (bf16)v.z; o[3] = (bf16)v.w;
        *(bf16x4*)&xb[i] = o;
    } else {
        int idx = (blk - MM) * 256 + threadIdx.x;   // n*1024 + k
        int n = idx >> 10, k = idx & 1023;
        int h = n >> 7, d = n & 127;
        float c = cosf(PI_F * freqs[n]);
        WbT1[idx] = (bf16)(W_proj[(size_t)h * (DD * 128) + (size_t)k * 128 + d] * c);
        WoT[idx]  = (bf16)(W_out[(size_t)k * DD + n]);
        if (idx < NB * DD) hm[idx] = 0.0f;
    }
}

// ============ 128x256x32 MFMA GEMM: 4 waves, 56KB LDS, 2 blocks/CU ============
// LDS map (bf16 elems): A-ring 3 x 4096 @0; B-ring 2 x 8192 @12288. Total 28672.
// Swizzle: physquad = quad ^ ((row>>1)&3); staging pre-swizzles global source.
// Ring invariants: A(t) -> slot t%3; B(t) -> buf t&1.  B(u+2) therefore goes to
// buf (u+2)&1 == BCUR (the buffer whose B(u) payload was consumed last K-step).

#define SCHED0 __builtin_amdgcn_sched_barrier(0)
#define BAR    SCHED0; __builtin_amdgcn_s_barrier(); SCHED0
#define LGKM0  asm volatile("s_waitcnt lgkmcnt(0)" ::: "memory"); SCHED0

#define RD_A(dst, off)                                                        \
    _Pragma("unroll") for (int m_ = 0; m_ < 4; ++m_)                          \
        dst[m_] = *(const bf16x8*)&sm[(off) + a_lane + m_ * 512];

#define RD_B(dst, off)                                                        \
    _Pragma("unroll") for (int n_ = 0; n_ < 4; ++n_)                          \
        dst[n_] = *(const bf16x8*)&sm[(off) + b_lane + n_ * 512];

#define MFMA_P(af, BR)                                                        \
    _Pragma("unroll") for (int m_ = 0; m_ < 4; ++m_)                          \
    _Pragma("unroll") for (int n_ = 0; n_ < 4; ++n_)                          \
        acc[(BR) + m_][n_] = __builtin_amdgcn_mfma_f32_16x16x32_bf16(         \
            af[m_], bc[n_], acc[(BR) + m_][n_], 0, 0, 0);

#define STG_A(U, AB)                                                          \
    gl2lds16(gA0 + (U) * 32, &sm[(AB) * 4096 + wv512]);                       \
    gl2lds16(gA1 + (U) * 32, &sm[(AB) * 4096 + 2048 + wv512]);

#define STG_B(U, BB)                                                          \
    gl2lds16(gB0 + (U) * 32, &sm[12288 + (BB) * 8192 + wv512]);               \
    gl2lds16(gB1 + (U) * 32, &sm[12288 + (BB) * 8192 + 2048 + wv512]);        \
    gl2lds16(gB2 + (U) * 32, &sm[12288 + (BB) * 8192 + 4096 + wv512]);        \
    gl2lds16(gB3 + (U) * 32, &sm[12288 + (BB) * 8192 + 6144 + wv512]);

// U: K-step; ACUR/AN2/ANX: A-ring slots u%3,(u+2)%3,(u+1)%3; BCUR=u&1; STG: stage u+2; RD: read-ahead u+1
#define KSTEP(U, ACUR, AN2, ANX, BCUR, STG, RD)                               \
    {                                                                         \
        BAR;                                                                  \
        if (STG) { STG_A((U) + 2, AN2); }                                     \
        LGKM0;                                                                \
        __builtin_amdgcn_s_setprio(1);                                        \
        MFMA_P(af0, 0);                                                       \
        RD_A(af1, (ACUR) * 4096 + 2048);                                      \
        __builtin_amdgcn_s_setprio(0);                                        \
        if (STG) { asm volatile("s_waitcnt vmcnt(2)" ::: "memory"); }         \
        else     { asm volatile("s_waitcnt vmcnt(0)" ::: "memory"); }         \
        SCHED0;                                                               \
        BAR;                                                                  \
        if (STG) { STG_B((U) + 2, (BCUR)); }                                  \
        LGKM0;                                                                \
        __builtin_amdgcn_s_setprio(1);                                        \
        MFMA_P(af1, 4);                                                       \
        if (RD) { RD_A(af0, (ANX) * 4096);                                    \
                  RD_B(bc, 12288 + (1 - (BCUR)) * 8192); }                    \
        __builtin_amdgcn_s_setprio(0);                                        \
        SCHED0;                                                               \
    }

// MODE 0: C=heads bf16 (stride 2048) + fused column sums -> hm.
// MODE 1: C=z bf16 (stride 2048) = acc + bias[col] + residb[row][col].
template <int MODE>
__global__ __launch_bounds__(256, 2)
void gemm128(const bf16* __restrict__ A, int lda, const bf16* __restrict__ Bt,
             bf16* __restrict__ Cstr, const bf16* __restrict__ residb,
             const float* __restrict__ bias, float* __restrict__ hm) {
    __shared__ bf16 sm[28672];                 // 56 KB
    const int tid = threadIdx.x;
    const int lane = tid & 63, w = tid >> 6;   // 4 waves, wave w owns cols [w*64, w*64+64)
    const int l15 = lane & 15, l4 = lane >> 4;
    const int wv512 = w * 512;

    // XCD-aware remap: per XCD, nt varies fastest -> A-panel live set ~2MB + B 2MB in L2
    int orig = blockIdx.x;
    int xcd = orig & 7, k = orig >> 3;         // k in 0..127
    const int mt = xcd * 32 + (k >> 2);        // 0..255
    const int nt = k & 3;                      // 0..3
    const int row0 = mt * 128, col0 = nt * 256;

    // LDS frag-read per-lane constants (swizzle collapses: (row>>1)&3 == (l15>>1)&3)
    const int aq = ((l4 ^ ((l15 >> 1) & 3)) << 3);
    const int a_lane = l15 * 32 + aq;
    const int b_lane = w * 2048 + l15 * 32 + aq;

    // staging pointers: thread t stages phys slot (row=t>>2 [+64i], quad=t&3);
    // source logical quad = (t&3) ^ ((t>>3)&3)
    const int srow = tid >> 2;
    const int sq = (tid & 3) ^ ((tid >> 3) & 3);
    const bf16* gA0 = A + (size_t)(row0 + srow) * lda + sq * 8;
    const bf16* gA1 = gA0 + (size_t)64 * lda;
    const bf16* gB0 = Bt + (size_t)(col0 + srow) * 1024 + sq * 8;
    const bf16* gB1 = gB0 + 64 * 1024;
    const bf16* gB2 = gB0 + 128 * 1024;
    const bf16* gB3 = gB0 + 192 * 1024;

    f32x4 acc[8][4] = {};
    bf16x8 af0[4], af1[4], bc[4];

    // prologue: A(0)->slot0, B(0)->buf0, A(1)->slot1, B(1)->buf1
    STG_A(0, 0); STG_B(0, 0); STG_A(1, 1); STG_B(1, 1);
    asm volatile("s_waitcnt vmcnt(6)" ::: "memory");
    BAR;
    RD_A(af0, 0);
    RD_B(bc, 12288);
    SCHED0;

    for (int uu = 0; uu < 30; uu += 6) {
#pragma unroll
        for (int v = 0; v < 6; ++v) {
            KSTEP(uu + v, (v) % 3, (v + 2) % 3, (v + 1) % 3, (v & 1), true, true);
        }
    }
    KSTEP(30, 0, 2, 1, 0, false, true);
    KSTEP(31, 1, 0, 2, 1, false, false);

    // ---- epilogue: strided C (row stride 2048 bf16, payload = first 1024) ----
    if (MODE == 0) {
        const int batch = row0 >> 13;
#pragma unroll
        for (int mf = 0; mf < 8; ++mf) {
            int rbase = row0 + mf * 16 + l4 * 4;
#pragma unroll
            for (int j = 0; j < 4; ++j) {
                size_t row = rbase + j;
#pragma unroll
                for (int nf = 0; nf < 4; ++nf) {
                    int col = col0 + w * 64 + nf * 16 + l15;
                    Cstr[row * 2048 + col] = (bf16)acc[mf][nf][j];
                }
            }
        }
#pragma unroll
        for (int nf = 0; nf < 4; ++nf) {
            float s = 0;
#pragma unroll
            for (int mf = 0; mf < 8; ++mf)
#pragma unroll
                for (int j = 0; j < 4; ++j) s += acc[mf][nf][j];
            int col = col0 + w * 64 + nf * 16 + l15;
            atomicAdd(&hm[batch * DD + col], s);
        }
    } else {
        float bi[4];
#pragma unroll
        for (int nf = 0; nf < 4; ++nf) bi[nf] = bias[col0 + w * 64 + nf * 16 + l15];
#pragma unroll
        for (int mf = 0; mf < 8; ++mf) {
            int rbase = row0 + mf * 16 + l4 * 4;
#pragma unroll
            for (int j = 0; j < 4; ++j) {
                size_t row = rbase + j;
#pragma unroll
                for (int nf = 0; nf < 4; ++nf) {
                    int col = col0 + w * 64 + nf * 16 + l15;
                    Cstr[row * 2048 + col] =
                        (bf16)(acc[mf][nf][j] + bi[nf] + (float)residb[row * 1024 + col]);
                }
            }
        }
    }
}

// ---- impedance MLP ----
__global__ __launch_bounds__(1024) void imp_k(const float* __restrict__ hm,
                                              const float* __restrict__ W_pol,
                                              const float* __restrict__ b_pol,
                                              const float* __restrict__ W_imp1,
                                              const float* __restrict__ b_imp1,
                                              const float* __restrict__ W_imp2,
                                              const float* __restrict__ b_imp2,
                                              float* __restrict__ imp_out,
                                              float* __restrict__ coeff) {
    __shared__ float pm_s[32][32];
    int tid = threadIdx.x;
    int bh = tid >> 5, p = tid & 31;
    int b = bh >> 3, h = bh & 7;
    float a = b_pol[h * 32 + p];
    for (int d = 0; d < 128; ++d)
        a += hm[b * DD + h * 128 + d] * (1.0f / SS) * W_pol[(h * 128 + d) * 32 + p];
    float pv = tanhf(a);
    pm_s[bh][p] = pv;
    __syncthreads();
    float ss = 0;
    for (int q = 0; q < 32; ++q) ss += pm_s[bh][q] * pm_s[bh][q];
    float pmv = pv / fmaxf(sqrtf(ss), 1e-12f);
    __syncthreads();
    pm_s[bh][p] = pmv;
    __syncthreads();
    if (tid < 256) {
        int b2 = tid >> 6, h2 = (tid >> 3) & 7, g = tid & 7;
        float dp = 0;
        for (int q = 0; q < 32; ++q) dp += pm_s[b2 * 8 + h2][q] * pm_s[b2 * 8 + g][q];
        float a2 = 0;
        for (int kk = 0; kk < 16; ++kk) {
            float zin = dp * W_imp1[kk] + b_imp1[kk];
            float zg = 0.5f * zin * (1.0f + erff(zin * 0.70710678118654752f));
            a2 += zg * W_imp2[kk];
        }
        float spin = a2 + b_imp2[0];
        float impv = (spin > 20.0f) ? spin : log1pf(expf(spin));
        if (h2 == g) impv = 0.0f;
        imp_out[tid] = impv;
        coeff[tid] = (h2 == g) ? 0.0f : 0.1f / (1.0f + impv);
    }
}

// ---- head mixing: heads (first half of row slot) -> merged (second half) ----
__global__ __launch_bounds__(256) void mix_k(const char* __restrict__ slots,
                                             const float* __restrict__ coeff,
                                             char* __restrict__ slots_w) {
    __shared__ float cf[64];
    int tid = threadIdx.x;
    size_t r0 = (size_t)blockIdx.x * 4;
    int b = (int)(r0 >> 13);
    if (tid < 64) cf[tid] = coeff[b * 64 + tid];
    __syncthreads();
    int lr = tid >> 6;
    int d2 = tid & 63;
    size_t r = r0 + lr;
    int s = (int)(r & (SS - 1));
    float cs = (float)(s + 1) * (1.0f / SS);
    const bf16* hrow = (const bf16*)(slots + r * 4096);
    bf16* mrow = (bf16*)(slots_w + r * 4096 + 2048);
    float v0[8], v1[8];
#pragma unroll
    for (int g = 0; g < 8; ++g) {
        bf16x2 v = *(const bf16x2*)&hrow[g * 128 + d2 * 2];
        v0[g] = (float)v[0]; v1[g] = (float)v[1];
    }
#pragma unroll
    for (int h = 0; h < 8; ++h) {
        float a0 = 0, a1 = 0;
#pragma unroll
        for (int g = 0; g < 8; ++g) {
            float c = cf[h * 8 + g];
            a0 += c * v0[g]; a1 += c * v1[g];
        }
        bf16x2 o;
        o[0] = (bf16)(v0[h] + cs * a0);
        o[1] = (bf16)(v1[h] + cs * a1);
        *(bf16x2*)&mrow[h * 128 + d2 * 2] = o;
    }
}

// ---- LayerNorm: read bf16 z from first 2KB of row slot, write fp32 y over slot ----
__global__ __launch_bounds__(256) void ln_k(char* __restrict__ slots,
                                            const float* __restrict__ gamma,
                                            const float* __restrict__ beta) {
    size_t r = blockIdx.x;
    int tid = threadIdx.x;
    const bf16* zrow = (const bf16*)(slots + r * 4096);
    float* yrow = (float*)(slots + r * 4096);
    int e0 = tid * 4;
    bf16x4 zv = *(const bf16x4*)&zrow[e0];
    float vx = (float)zv[0], vy = (float)zv[1], vz = (float)zv[2], vw = (float)zv[3];
    float sum = vx + vy + vz + vw;
    float sq  = vx * vx + vy * vy + vz * vz + vw * vw;
    for (int off = 32; off > 0; off >>= 1) {
        sum += __shfl_down(sum, off);
        sq  += __shfl_down(sq, off);
    }
    __shared__ float red[8];
    int lane = tid & 63, wv = tid >> 6;
    if (lane == 0) { red[wv] = sum; red[4 + wv] = sq; }
    __syncthreads();
    float tot = red[0] + red[1] + red[2] + red[3];
    float tsq = red[4] + red[5] + red[6] + red[7];
    float mu  = tot * (1.0f / DD);
    float var = tsq * (1.0f / DD) - mu * mu;
    float rs  = rsqrtf(var + 1e-5f);
    float4 g4 = *(const float4*)&gamma[e0];
    float4 b4 = *(const float4*)&beta[e0];
    float4 o;
    o.x = (vx - mu) * rs * g4.x + b4.x;
    o.y = (vy - mu) * rs * g4.y + b4.y;
    o.z = (vz - mu) * rs * g4.z + b4.z;
    o.w = (vw - mu) * rs * g4.w + b4.w;
    *(float4*)&yrow[e0] = o;
}

extern "C" void kernel_launch(void* const* d_in, const int* in_sizes, int n_in,
                              void* d_out, int out_size, void* d_ws, size_t ws_size,
                              hipStream_t stream) {
    const float* x      = (const float*)d_in[0];
    const float* W_proj = (const float*)d_in[1];
    const float* freqs  = (const float*)d_in[2];
    const float* W_pol  = (const float*)d_in[3];
    const float* b_pol  = (const float*)d_in[4];
    const float* W_imp1 = (const float*)d_in[5];
    const float* b_imp1 = (const float*)d_in[6];
    const float* W_imp2 = (const float*)d_in[7];
    const float* b_imp2 = (const float*)d_in[8];
    const float* W_out  = (const float*)d_in[9];
    const float* b_out  = (const float*)d_in[10];
    const float* gamma  = (const float*)d_in[11];
    const float* beta   = (const float*)d_in[12];

    char* ws = (char*)d_ws;
    bf16* xb     = (bf16*)ws;                                  // 64MB
    bf16* WbT1   = (bf16*)(ws + ((size_t)64 << 20));           // 2MB
    bf16* WoT    = (bf16*)(ws + ((size_t)66 << 20));           // 2MB
    float* hm    = (float*)(ws + ((size_t)68 << 20));          // 16KB
    float* coeff = (float*)(ws + ((size_t)68 << 20) + 16384);  // 1KB

    char* slots = (char*)d_out;                      // 128MB of 4KB row slots
    float* imp_out = (float*)d_out + (size_t)MM * DD;

    prep_all<<<MM + 4096, 256, 0, stream>>>(x, xb, W_proj, freqs, W_out,
                                            WbT1, WoT, hm);

    // GEMM1: heads -> first half of row slots (+ hm column sums)
    gemm128<0><<<1024, 256, 0, stream>>>(xb, 1024, WbT1, (bf16*)slots,
                                         nullptr, nullptr, hm);

    imp_k<<<1, 1024, 0, stream>>>(hm, W_pol, b_pol, W_imp1, b_imp1, W_imp2, b_imp2,
                                  imp_out, coeff);

    mix_k<<<MM / 4, 256, 0, stream>>>(slots, coeff, slots);    // heads -> merged

    // GEMM2: A = merged (second half, stride 2048); z -> first half of slots
    gemm128<1><<<1024, 256, 0, stream>>>((const bf16*)slots + 1024, 2048, WoT,
                                         (bf16*)slots, xb, b_out, nullptr);

    ln_k<<<MM, 256, 0, stream>>>(slots, gamma, beta);
}

// Round 7
// 275.603 us; speedup vs baseline: 1.0132x; 1.0132x over previous
//
#include <hip/hip_runtime.h>
#include <hip/hip_bf16.h>
#include <math.h>

typedef __bf16 bf16;
typedef __bf16 bf16x2 __attribute__((ext_vector_type(2)));
typedef __bf16 bf16x4 __attribute__((ext_vector_type(4)));
typedef __bf16 bf16x8 __attribute__((ext_vector_type(8)));
typedef float  f32x4  __attribute__((ext_vector_type(4)));

#define NB 4
#define SS 8192
#define DD 1024
#define MM 32768
#define KK 1024
#define NN 1024
#define PI_F 3.14159265358979323846f

__device__ __forceinline__ void gl2lds16(const bf16* g, bf16* l) {
    __builtin_amdgcn_global_load_lds(
        (const __attribute__((address_space(1))) void*)g,
        (__attribute__((address_space(3))) void*)l, 16, 0, 0);
}

// ---- fused prep: x->bf16 cast (blocks [0,MM)), W build + hm zero ----
__global__ __launch_bounds__(256) void prep_all(const float* __restrict__ x,
                                                bf16* __restrict__ xb,
                                                const float* __restrict__ W_proj,
                                                const float* __restrict__ freqs,
                                                const float* __restrict__ W_out,
                                                bf16* __restrict__ WbT1,
                                                bf16* __restrict__ WoT,
                                                float* __restrict__ hm) {
    int blk = blockIdx.x;
    if (blk < MM) {
        size_t i = (size_t)blk * 1024 + threadIdx.x * 4;
        float4 v = *(const float4*)&x[i];
        bf16x4 o;
        o[0] = (bf16)v.x; o[1] = (bf16)v.y; o[2] = (bf16)v.z; o[3] = (bf16)v.w;
        *(bf16x4*)&xb[i] = o;
    } else {
        int idx = (blk - MM) * 256 + threadIdx.x;   // n*1024 + k
        int n = idx >> 10, k = idx & 1023;
        int h = n >> 7, d = n & 127;
        float c = cosf(PI_F * freqs[n]);
        WbT1[idx] = (bf16)(W_proj[(size_t)h * (DD * 128) + (size_t)k * 128 + d] * c);
        WoT[idx]  = (bf16)(W_out[(size_t)k * DD + n]);
        if (idx < NB * DD) hm[idx] = 0.0f;
    }
}

// ========== 256x256x64 8-phase MFMA GEMM (m201-style template) ==========
// 512 thr (8 waves 2M x 4N), 128KB LDS. Buffers static: even K-tile -> buf0.
// LDS elems: A-buf0 @0, A-buf1 @16384, B-buf0 @32768, B-buf1 @49152;
// each buf 256 rows x 64 cols, halves of 128 rows (8192 elems).
// Phase: {stage 1 half-tile; ds-reads; [lgkm(8) if 12]; BAR; lgkm0; prio1;
//         16 MFMA; prio0; BAR}.  vmcnt(4) @p4/p8 certifies next tile's 4
//         halves, keeps 2 half-tiles in flight (T4).  Swizzle: physquad =
//         quad ^ (row&7), pre-swizzled global source (conflicts=0, R4).

#define SCHED0 __builtin_amdgcn_sched_barrier(0)
#define BAR    SCHED0; __builtin_amdgcn_s_barrier(); SCHED0
#define LGKM0  asm volatile("s_waitcnt lgkmcnt(0)" ::: "memory"); SCHED0
#define PRIO1  __builtin_amdgcn_s_setprio(1)
#define PRIO0  __builtin_amdgcn_s_setprio(0)
#define VMC(N) asm volatile("s_waitcnt vmcnt(" #N ")" ::: "memory")
#define NOPS   ((void)0)

#define STG(g0, g1, uk, ldsBase)                                  \
    gl2lds16((g0) + (uk), &sm[(ldsBase) + w * 512]);              \
    gl2lds16((g1) + (uk), &sm[(ldsBase) + 4096 + w * 512]);

#define READ_A2(MQ, ab)                                                          \
    _Pragma("unroll") for (int m_ = 0; m_ < 4; ++m_) {                           \
        a[m_ * 2 + 0] = *(const bf16x8*)&sm[(ab) + aoff0 + ((MQ)*64 + m_*16)*64];\
        a[m_ * 2 + 1] = *(const bf16x8*)&sm[(ab) + aoff1 + ((MQ)*64 + m_*16)*64];\
    }
#define READ_B2(NQ, bfr, bb)                                                     \
    _Pragma("unroll") for (int n_ = 0; n_ < 2; ++n_) {                           \
        bfr[n_ * 2 + 0] = *(const bf16x8*)&sm[(bb) + boff0 + ((NQ)*32 + n_*16)*64];\
        bfr[n_ * 2 + 1] = *(const bf16x8*)&sm[(bb) + boff1 + ((NQ)*32 + n_*16)*64];\
    }

#define MFMA_Q(MQ, NQ, bfr)                                                    \
    _Pragma("unroll") for (int m_ = 0; m_ < 4; ++m_)                           \
    _Pragma("unroll") for (int n_ = 0; n_ < 2; ++n_)                           \
    _Pragma("unroll") for (int ks_ = 0; ks_ < 2; ++ks_)                        \
        acc[(MQ) * 4 + m_][(NQ) * 2 + n_] =                                    \
            __builtin_amdgcn_mfma_f32_16x16x32_bf16(                           \
                a[m_ * 2 + ks_], bfr[n_ * 2 + ks_],                            \
                acc[(MQ) * 4 + m_][(NQ) * 2 + n_], 0, 0, 0);

// one iteration = K-tiles t (buf0), t+1 (buf1); stages per phase p1..p8:
// A(t+1)h0, A(t+1)h1, B(t+2)h0, B(t+2)h1, A(t+2)h0, A(t+2)h1, B(t+3)h0, B(t+3)h1
#define ITER(uk1, STG3, STG4, STG5, STG6, STG7, STG8, VM4, VM8)                \
  { /* p1: MFMA(0,0) tile t */                                                 \
    STG(gA00, gA01, (uk1), 16384);                                             \
    READ_A2(0, 0); READ_B2(0, blo, 32768);                                     \
    asm volatile("s_waitcnt lgkmcnt(8)" ::: "memory");                         \
    BAR; LGKM0; PRIO1; MFMA_Q(0, 0, blo); PRIO0; BAR;                          \
    /* p2: MFMA(0,1) */                                                        \
    STG(gA10, gA11, (uk1), 16384 + 8192);                                      \
    READ_B2(1, bhi, 32768);                                                    \
    BAR; LGKM0; PRIO1; MFMA_Q(0, 1, bhi); PRIO0; BAR;                          \
    /* p3: MFMA(1,1) */                                                        \
    STG3; READ_A2(1, 0);                                                       \
    BAR; LGKM0; PRIO1; MFMA_Q(1, 1, bhi); PRIO0; BAR;                          \
    /* p4: MFMA(1,0); certify tile t+1 */                                      \
    STG4; VM4;                                                                 \
    BAR; PRIO1; MFMA_Q(1, 0, blo); PRIO0; BAR;                                 \
    /* p5: MFMA(0,0) tile t+1 */                                               \
    STG5; READ_A2(0, 16384); READ_B2(0, blo, 49152);                           \
    asm volatile("s_waitcnt lgkmcnt(8)" ::: "memory");                         \
    BAR; LGKM0; PRIO1; MFMA_Q(0, 0, blo); PRIO0; BAR;                          \
    /* p6: MFMA(0,1) */                                                        \
    STG6; READ_B2(1, bhi, 49152);                                              \
    BAR; LGKM0; PRIO1; MFMA_Q(0, 1, bhi); PRIO0; BAR;                          \
    /* p7: MFMA(1,1) */                                                        \
    STG7; READ_A2(1, 16384);                                                   \
    BAR; LGKM0; PRIO1; MFMA_Q(1, 1, bhi); PRIO0; BAR;                          \
    /* p8: MFMA(1,0); certify tile t+2 */                                      \
    STG8; VM8;                                                                 \
    BAR; PRIO1; MFMA_Q(1, 0, blo); PRIO0; BAR;                                 \
  }

// MODE 0: C=heads bf16 (stride 2048) + fused column sums -> hm.
// MODE 1: C=z bf16 (stride 2048) = acc + bias[col] + residb[row][col].
template <int MODE>
__global__ __launch_bounds__(512, 2)
void gemm256(const bf16* __restrict__ A, int lda, const bf16* __restrict__ Bt,
             bf16* __restrict__ Cstr, const bf16* __restrict__ residb,
             const float* __restrict__ bias, float* __restrict__ hm) {
    __shared__ bf16 sm[65536];                 // 128 KB
    const int tid = threadIdx.x;
    const int lane = tid & 63, w = tid >> 6;
    const int wr = w >> 2, wc = w & 3;         // 2(M) x 4(N) waves
    const int l15 = lane & 15, l4 = lane >> 4;

    int wg = blockIdx.x;
    int swz = (wg & 7) * 64 + (wg >> 3);       // XCD-aware bijective swizzle
    const int mt = swz >> 2, ntile = swz & 3;
    const int row0 = mt * 256, col0 = ntile * 256;

    const int aoff0 = (wr * 128 + l15) * 64 + ((l4 ^ (l15 & 7)) << 3);
    const int aoff1 = aoff0 ^ 32;
    const int boff0 = (wc * 64 + l15) * 64 + ((l4 ^ (l15 & 7)) << 3);
    const int boff1 = boff0 ^ 32;

    const int srow = tid >> 3;                       // 0..63
    const int scb  = (tid & 7) ^ (srow & 7);
    const bf16* gA00 = A + (size_t)(row0 + srow) * lda + scb * 8;
    const bf16* gA01 = gA00 + (size_t)64 * lda;
    const bf16* gA10 = gA00 + (size_t)128 * lda;
    const bf16* gA11 = gA00 + (size_t)192 * lda;
    const bf16* gB00 = Bt + (size_t)(col0 + srow) * 1024 + scb * 8;
    const bf16* gB01 = gB00 + 64 * 1024;
    const bf16* gB10 = gB00 + 128 * 1024;
    const bf16* gB11 = gB00 + 192 * 1024;

    f32x4 acc[8][4] = {};
    bf16x8 a[8], blo[4], bhi[4];

    // prologue: tiles 0 and 1 fully staged, drained, barriered
    STG(gA00, gA01, 0,  0);     STG(gA10, gA11, 0,  8192);
    STG(gB00, gB01, 0,  32768); STG(gB10, gB11, 0,  40960);
    STG(gA00, gA01, 64, 16384); STG(gA10, gA11, 64, 24576);
    STG(gB00, gB01, 64, 49152); STG(gB10, gB11, 64, 57344);
    VMC(0);
    BAR;

#pragma unroll 1
    for (int i = 0; i < 7; ++i) {
        const int uk1 = (2 * i + 1) * 64;
        const int uk2 = (2 * i + 2) * 64;
        const int uk3 = (2 * i + 3) * 64;
        ITER(uk1,
             STG(gB00, gB01, uk2, 32768), STG(gB10, gB11, uk2, 40960),
             STG(gA00, gA01, uk2, 0),     STG(gA10, gA11, uk2, 8192),
             STG(gB00, gB01, uk3, 49152), STG(gB10, gB11, uk3, 57344),
             VMC(4), VMC(4));
    }
    // last iteration (tiles 14,15): only A(15) stages; vmcnt(0) certifies all
    ITER(960, NOPS, NOPS, NOPS, NOPS, NOPS, NOPS, VMC(0), NOPS);

    // ---- epilogue: strided C (row stride 2048 bf16, payload = first 1024) ----
    if (MODE == 0) {
        const int batch = row0 >> 13;
#pragma unroll
        for (int mg = 0; mg < 8; ++mg) {
            int rbase = row0 + wr * 128 + (mg >> 2) * 64 + (mg & 3) * 16 + l4 * 4;
#pragma unroll
            for (int j = 0; j < 4; ++j) {
                size_t row = rbase + j;
#pragma unroll
                for (int ng = 0; ng < 4; ++ng) {
                    int col = col0 + wc * 64 + ng * 16 + l15;
                    Cstr[row * 2048 + col] = (bf16)acc[mg][ng][j];
                }
            }
        }
#pragma unroll
        for (int ng = 0; ng < 4; ++ng) {
            float s = 0;
#pragma unroll
            for (int mg = 0; mg < 8; ++mg)
#pragma unroll
                for (int j = 0; j < 4; ++j) s += acc[mg][ng][j];
            int col = col0 + wc * 64 + ng * 16 + l15;
            atomicAdd(&hm[batch * DD + col], s);
        }
    } else {
        float bi[4];
#pragma unroll
        for (int ng = 0; ng < 4; ++ng) bi[ng] = bias[col0 + wc * 64 + ng * 16 + l15];
#pragma unroll
        for (int mg = 0; mg < 8; ++mg) {
            int rbase = row0 + wr * 128 + (mg >> 2) * 64 + (mg & 3) * 16 + l4 * 4;
#pragma unroll
            for (int j = 0; j < 4; ++j) {
                size_t row = rbase + j;
#pragma unroll
                for (int ng = 0; ng < 4; ++ng) {
                    int col = col0 + wc * 64 + ng * 16 + l15;
                    Cstr[row * 2048 + col] =
                        (bf16)(acc[mg][ng][j] + bi[ng] + (float)residb[row * 1024 + col]);
                }
            }
        }
    }
}

// ---- impedance MLP ----
__global__ __launch_bounds__(1024) void imp_k(const float* __restrict__ hm,
                                              const float* __restrict__ W_pol,
                                              const float* __restrict__ b_pol,
                                              const float* __restrict__ W_imp1,
                                              const float* __restrict__ b_imp1,
                                              const float* __restrict__ W_imp2,
                                              const float* __restrict__ b_imp2,
                                              float* __restrict__ imp_out,
                                              float* __restrict__ coeff) {
    __shared__ float pm_s[32][32];
    int tid = threadIdx.x;
    int bh = tid >> 5, p = tid & 31;
    int b = bh >> 3, h = bh & 7;
    float a = b_pol[h * 32 + p];
    for (int d = 0; d < 128; ++d)
        a += hm[b * DD + h * 128 + d] * (1.0f / SS) * W_pol[(h * 128 + d) * 32 + p];
    float pv = tanhf(a);
    pm_s[bh][p] = pv;
    __syncthreads();
    float ss = 0;
    for (int q = 0; q < 32; ++q) ss += pm_s[bh][q] * pm_s[bh][q];
    float pmv = pv / fmaxf(sqrtf(ss), 1e-12f);
    __syncthreads();
    pm_s[bh][p] = pmv;
    __syncthreads();
    if (tid < 256) {
        int b2 = tid >> 6, h2 = (tid >> 3) & 7, g = tid & 7;
        float dp = 0;
        for (int q = 0; q < 32; ++q) dp += pm_s[b2 * 8 + h2][q] * pm_s[b2 * 8 + g][q];
        float a2 = 0;
        for (int kk = 0; kk < 16; ++kk) {
            float zin = dp * W_imp1[kk] + b_imp1[kk];
            float zg = 0.5f * zin * (1.0f + erff(zin * 0.70710678118654752f));
            a2 += zg * W_imp2[kk];
        }
        float spin = a2 + b_imp2[0];
        float impv = (spin > 20.0f) ? spin : log1pf(expf(spin));
        if (h2 == g) impv = 0.0f;
        imp_out[tid] = impv;
        coeff[tid] = (h2 == g) ? 0.0f : 0.1f / (1.0f + impv);
    }
}

// ---- head mixing: heads (first half of row slot) -> merged (second half) ----
__global__ __launch_bounds__(256) void mix_k(const char* __restrict__ slots,
                                             const float* __restrict__ coeff,
                                             char* __restrict__ slots_w) {
    __shared__ float cf[64];
    int tid = threadIdx.x;
    size_t r0 = (size_t)blockIdx.x * 4;
    int b = (int)(r0 >> 13);
    if (tid < 64) cf[tid] = coeff[b * 64 + tid];
    __syncthreads();
    int lr = tid >> 6;
    int d2 = tid & 63;
    size_t r = r0 + lr;
    int s = (int)(r & (SS - 1));
    float cs = (float)(s + 1) * (1.0f / SS);
    const bf16* hrow = (const bf16*)(slots + r * 4096);
    bf16* mrow = (bf16*)(slots_w + r * 4096 + 2048);
    float v0[8], v1[8];
#pragma unroll
    for (int g = 0; g < 8; ++g) {
        bf16x2 v = *(const bf16x2*)&hrow[g * 128 + d2 * 2];
        v0[g] = (float)v[0]; v1[g] = (float)v[1];
    }
#pragma unroll
    for (int h = 0; h < 8; ++h) {
        float a0 = 0, a1 = 0;
#pragma unroll
        for (int g = 0; g < 8; ++g) {
            float c = cf[h * 8 + g];
            a0 += c * v0[g]; a1 += c * v1[g];
        }
        bf16x2 o;
        o[0] = (bf16)(v0[h] + cs * a0);
        o[1] = (bf16)(v1[h] + cs * a1);
        *(bf16x2*)&mrow[h * 128 + d2 * 2] = o;
    }
}

// ---- LayerNorm: read bf16 z from first 2KB of row slot, write fp32 y over slot ----
__global__ __launch_bounds__(256) void ln_k(char* __restrict__ slots,
                                            const float* __restrict__ gamma,
                                            const float* __restrict__ beta) {
    size_t r = blockIdx.x;
    int tid = threadIdx.x;
    const bf16* zrow = (const bf16*)(slots + r * 4096);
    float* yrow = (float*)(slots + r * 4096);
    int e0 = tid * 4;
    bf16x4 zv = *(const bf16x4*)&zrow[e0];
    float vx = (float)zv[0], vy = (float)zv[1], vz = (float)zv[2], vw = (float)zv[3];
    float sum = vx + vy + vz + vw;
    float sq  = vx * vx + vy * vy + vz * vz + vw * vw;
    for (int off = 32; off > 0; off >>= 1) {
        sum += __shfl_down(sum, off);
        sq  += __shfl_down(sq, off);
    }
    __shared__ float red[8];
    int lane = tid & 63, wv = tid >> 6;
    if (lane == 0) { red[wv] = sum; red[4 + wv] = sq; }
    __syncthreads();
    float tot = red[0] + red[1] + red[2] + red[3];
    float tsq = red[4] + red[5] + red[6] + red[7];
    float mu  = tot * (1.0f / DD);
    float var = tsq * (1.0f / DD) - mu * mu;
    float rs  = rsqrtf(var + 1e-5f);
    float4 g4 = *(const float4*)&gamma[e0];
    float4 b4 = *(const float4*)&beta[e0];
    float4 o;
    o.x = (vx - mu) * rs * g4.x + b4.x;
    o.y = (vy - mu) * rs * g4.y + b4.y;
    o.z = (vz - mu) * rs * g4.z + b4.z;
    o.w = (vw - mu) * rs * g4.w + b4.w;
    *(float4*)&yrow[e0] = o;
}

extern "C" void kernel_launch(void* const* d_in, const int* in_sizes, int n_in,
                              void* d_out, int out_size, void* d_ws, size_t ws_size,
                              hipStream_t stream) {
    const float* x      = (const float*)d_in[0];
    const float* W_proj = (const float*)d_in[1];
    const float* freqs  = (const float*)d_in[2];
    const float* W_pol  = (const float*)d_in[3];
    const float* b_pol  = (const float*)d_in[4];
    const float* W_imp1 = (const float*)d_in[5];
    const float* b_imp1 = (const float*)d_in[6];
    const float* W_imp2 = (const float*)d_in[7];
    const float* b_imp2 = (const float*)d_in[8];
    const float* W_out  = (const float*)d_in[9];
    const float* b_out  = (const float*)d_in[10];
    const float* gamma  = (const float*)d_in[11];
    const float* beta   = (const float*)d_in[12];

    char* ws = (char*)d_ws;
    bf16* xb     = (bf16*)ws;                                  // 64MB
    bf16* WbT1   = (bf16*)(ws + ((size_t)64 << 20));           // 2MB
    bf16* WoT    = (bf16*)(ws + ((size_t)66 << 20));           // 2MB
    float* hm    = (float*)(ws + ((size_t)68 << 20));          // 16KB
    float* coeff = (float*)(ws + ((size_t)68 << 20) + 16384);  // 1KB

    char* slots = (char*)d_out;                      // 128MB of 4KB row slots
    float* imp_out = (float*)d_out + (size_t)MM * DD;

    prep_all<<<MM + 4096, 256, 0, stream>>>(x, xb, W_proj, freqs, W_out,
                                            WbT1, WoT, hm);

    // GEMM1: heads -> first half of row slots (+ hm column sums)
    gemm256<0><<<512, 512, 0, stream>>>(xb, 1024, WbT1, (bf16*)slots,
                                        nullptr, nullptr, hm);

    imp_k<<<1, 1024, 0, stream>>>(hm, W_pol, b_pol, W_imp1, b_imp1, W_imp2, b_imp2,
                                  imp_out, coeff);

    mix_k<<<MM / 4, 256, 0, stream>>>(slots, coeff, slots);    // heads -> merged

    // GEMM2: A = merged (second half, stride 2048); z -> first half of slots
    gemm256<1><<<512, 512, 0, stream>>>((const bf16*)slots + 1024, 2048, WoT,
                                        (bf16*)slots, xb, b_out, nullptr);

    ln_k<<<MM, 256, 0, stream>>>(slots, gamma, beta);
}

// Round 8
// 266.065 us; speedup vs baseline: 1.0495x; 1.0358x over previous
//
#include <hip/hip_runtime.h>
#include <hip/hip_bf16.h>
#include <math.h>

typedef __bf16 bf16;
typedef __bf16 bf16x2 __attribute__((ext_vector_type(2)));
typedef __bf16 bf16x4 __attribute__((ext_vector_type(4)));
typedef __bf16 bf16x8 __attribute__((ext_vector_type(8)));
typedef float  f32x4  __attribute__((ext_vector_type(4)));

#define NB 4
#define SS 8192
#define DD 1024
#define MM 32768
#define KK 1024
#define NN 1024
#define PI_F 3.14159265358979323846f

__device__ __forceinline__ void gl2lds16(const bf16* g, bf16* l) {
    __builtin_amdgcn_global_load_lds(
        (const __attribute__((address_space(1))) void*)g,
        (__attribute__((address_space(3))) void*)l, 16, 0, 0);
}

// ---- fused prep: x->bf16 cast (blocks [0,MM)), W build + hm zero ----
__global__ __launch_bounds__(256) void prep_all(const float* __restrict__ x,
                                                bf16* __restrict__ xb,
                                                const float* __restrict__ W_proj,
                                                const float* __restrict__ freqs,
                                                const float* __restrict__ W_out,
                                                bf16* __restrict__ WbT1,
                                                bf16* __restrict__ WoT,
                                                float* __restrict__ hm) {
    int blk = blockIdx.x;
    if (blk < MM) {
        size_t i = (size_t)blk * 1024 + threadIdx.x * 4;
        float4 v = *(const float4*)&x[i];
        bf16x4 o;
        o[0] = (bf16)v.x; o[1] = (bf16)v.y; o[2] = (bf16)v.z; o[3] = (bf16)v.w;
        *(bf16x4*)&xb[i] = o;
    } else {
        int idx = (blk - MM) * 256 + threadIdx.x;   // n*1024 + k
        int n = idx >> 10, k = idx & 1023;
        int h = n >> 7, d = n & 127;
        float c = cosf(PI_F * freqs[n]);
        WbT1[idx] = (bf16)(W_proj[(size_t)h * (DD * 128) + (size_t)k * 128 + d] * c);
        WoT[idx]  = (bf16)(W_out[(size_t)k * DD + n]);
        if (idx < NB * DD) hm[idx] = 0.0f;
    }
}

// ========== 256x256x64 8-phase MFMA GEMM — compiler-managed intra-phase ==========
// 512 thr (8 waves 2M x 4N), 128KB LDS. Even K-tile -> buf0, odd -> buf1.
// LDS elems: A-buf0 @0, A-buf1 @16384, B-buf0 @32768, B-buf1 @49152.
// One raw s_barrier per phase; NO lgkm asm / sched_barrier in the loop —
// ds_read->MFMA ordering via value deps (compiler emits counted lgkmcnt and
// interleaves reads among MFMAs).  vmcnt(4) at p4/p8 certs the next tile.
// Stage/WAR audit: stage(X) always >=1 barrier after last value-consumed read
// of X's region; certs one phase-quad before first read of staged data.

#define FENCE  asm volatile("" ::: "memory")
#define BARRIER do { FENCE; __builtin_amdgcn_s_barrier(); FENCE; } while (0)
#define PRIO1  __builtin_amdgcn_s_setprio(1)
#define PRIO0  __builtin_amdgcn_s_setprio(0)
#define VMC(N) asm volatile("s_waitcnt vmcnt(" #N ")" ::: "memory")
#define NOPS   ((void)0)

#define STG(g0, g1, uk, ldsBase)                                  \
    gl2lds16((g0) + (uk), &sm[(ldsBase) + w * 512]);              \
    gl2lds16((g1) + (uk), &sm[(ldsBase) + 4096 + w * 512]);

#define READ_A2(MQ, ab)                                                          \
    _Pragma("unroll") for (int m_ = 0; m_ < 4; ++m_) {                           \
        a[m_ * 2 + 0] = *(const bf16x8*)&sm[(ab) + aoff0 + ((MQ)*64 + m_*16)*64];\
        a[m_ * 2 + 1] = *(const bf16x8*)&sm[(ab) + aoff1 + ((MQ)*64 + m_*16)*64];\
    }
#define READ_B2(NQ, bfr, bb)                                                     \
    _Pragma("unroll") for (int n_ = 0; n_ < 2; ++n_) {                           \
        bfr[n_ * 2 + 0] = *(const bf16x8*)&sm[(bb) + boff0 + ((NQ)*32 + n_*16)*64];\
        bfr[n_ * 2 + 1] = *(const bf16x8*)&sm[(bb) + boff1 + ((NQ)*32 + n_*16)*64];\
    }

#define MFMA_Q(MQ, NQ, bfr)                                                    \
    _Pragma("unroll") for (int m_ = 0; m_ < 4; ++m_)                           \
    _Pragma("unroll") for (int n_ = 0; n_ < 2; ++n_)                           \
    _Pragma("unroll") for (int ks_ = 0; ks_ < 2; ++ks_)                        \
        acc[(MQ) * 4 + m_][(NQ) * 2 + n_] =                                    \
            __builtin_amdgcn_mfma_f32_16x16x32_bf16(                           \
                a[m_ * 2 + ks_], bfr[n_ * 2 + ks_],                            \
                acc[(MQ) * 4 + m_][(NQ) * 2 + n_], 0, 0, 0);

// iteration = K-tiles t (buf0), t+1 (buf1); stages p1..p8:
// A(t+1)h0, A(t+1)h1, B(t+2)h0, B(t+2)h1, A(t+2)h0, A(t+2)h1, B(t+3)h0, B(t+3)h1
#define ITER(uk1, STG3, STG4, STG5, STG6, STG7, STG8, VM4, VM8)                \
  { /* p1 */                                                                   \
    BARRIER; STG(gA00, gA01, (uk1), 16384);                                    \
    PRIO1; READ_A2(0, 0); READ_B2(0, blo, 32768);                              \
    MFMA_Q(0, 0, blo); PRIO0;                                                  \
    /* p2 */                                                                   \
    BARRIER; STG(gA10, gA11, (uk1), 24576);                                    \
    PRIO1; READ_B2(1, bhi, 32768); MFMA_Q(0, 1, bhi); PRIO0;                   \
    /* p3 */                                                                   \
    BARRIER; STG3;                                                             \
    PRIO1; READ_A2(1, 0); MFMA_Q(1, 1, bhi); PRIO0;                            \
    /* p4: certify tile t+1 */                                                 \
    BARRIER; STG4; VM4;                                                        \
    PRIO1; MFMA_Q(1, 0, blo); PRIO0;                                           \
    /* p5 */                                                                   \
    BARRIER; STG5;                                                             \
    PRIO1; READ_A2(0, 16384); READ_B2(0, blo, 49152);                          \
    MFMA_Q(0, 0, blo); PRIO0;                                                  \
    /* p6 */                                                                   \
    BARRIER; STG6;                                                             \
    PRIO1; READ_B2(1, bhi, 49152); MFMA_Q(0, 1, bhi); PRIO0;                   \
    /* p7 */                                                                   \
    BARRIER; STG7;                                                             \
    PRIO1; READ_A2(1, 16384); MFMA_Q(1, 1, bhi); PRIO0;                        \
    /* p8: certify tile t+2 */                                                 \
    BARRIER; STG8; VM8;                                                        \
    PRIO1; MFMA_Q(1, 0, blo); PRIO0;                                           \
  }

// MODE 0: C=heads bf16 (stride 2048) + fused column sums -> hm.
// MODE 1: C=z bf16 (stride 2048) = acc + bias[col] + residb[row][col].
template <int MODE>
__global__ __launch_bounds__(512, 2)
void gemm256(const bf16* __restrict__ A, int lda, const bf16* __restrict__ Bt,
             bf16* __restrict__ Cstr, const bf16* __restrict__ residb,
             const float* __restrict__ bias, float* __restrict__ hm) {
    __shared__ bf16 sm[65536];                 // 128 KB
    const int tid = threadIdx.x;
    const int lane = tid & 63, w = tid >> 6;
    const int wr = w >> 2, wc = w & 3;         // 2(M) x 4(N) waves
    const int l15 = lane & 15, l4 = lane >> 4;

    int wg = blockIdx.x;
    int swz = (wg & 7) * 64 + (wg >> 3);       // XCD-aware bijective swizzle
    const int mt = swz >> 2, ntile = swz & 3;
    const int row0 = mt * 256, col0 = ntile * 256;

    const int aoff0 = (wr * 128 + l15) * 64 + ((l4 ^ (l15 & 7)) << 3);
    const int aoff1 = aoff0 ^ 32;
    const int boff0 = (wc * 64 + l15) * 64 + ((l4 ^ (l15 & 7)) << 3);
    const int boff1 = boff0 ^ 32;

    const int srow = tid >> 3;                       // 0..63
    const int scb  = (tid & 7) ^ (srow & 7);
    const bf16* gA00 = A + (size_t)(row0 + srow) * lda + scb * 8;
    const bf16* gA01 = gA00 + (size_t)64 * lda;
    const bf16* gA10 = gA00 + (size_t)128 * lda;
    const bf16* gA11 = gA00 + (size_t)192 * lda;
    const bf16* gB00 = Bt + (size_t)(col0 + srow) * 1024 + scb * 8;
    const bf16* gB01 = gB00 + 64 * 1024;
    const bf16* gB10 = gB00 + 128 * 1024;
    const bf16* gB11 = gB00 + 192 * 1024;

    f32x4 acc[8][4] = {};
    bf16x8 a[8], blo[4], bhi[4];

    // prologue: tiles 0 and 1 fully staged and certified (p1 opens with BARRIER)
    STG(gA00, gA01, 0,  0);     STG(gA10, gA11, 0,  8192);
    STG(gB00, gB01, 0,  32768); STG(gB10, gB11, 0,  40960);
    STG(gA00, gA01, 64, 16384); STG(gA10, gA11, 64, 24576);
    STG(gB00, gB01, 64, 49152); STG(gB10, gB11, 64, 57344);
    VMC(0);

#pragma unroll 1
    for (int i = 0; i < 7; ++i) {
        const int uk1 = (2 * i + 1) * 64;
        const int uk2 = (2 * i + 2) * 64;
        const int uk3 = (2 * i + 3) * 64;
        ITER(uk1,
             STG(gB00, gB01, uk2, 32768), STG(gB10, gB11, uk2, 40960),
             STG(gA00, gA01, uk2, 0),     STG(gA10, gA11, uk2, 8192),
             STG(gB00, gB01, uk3, 49152), STG(gB10, gB11, uk3, 57344),
             VMC(4), VMC(4));
    }
    // last iteration (tiles 14,15): only A(15) stages; vmcnt(0) certifies all
    ITER(960, NOPS, NOPS, NOPS, NOPS, NOPS, NOPS, VMC(0), NOPS);

    // ---- epilogue: strided C (row stride 2048 bf16, payload = first 1024) ----
    if (MODE == 0) {
        const int batch = row0 >> 13;
#pragma unroll
        for (int mg = 0; mg < 8; ++mg) {
            int rbase = row0 + wr * 128 + (mg >> 2) * 64 + (mg & 3) * 16 + l4 * 4;
#pragma unroll
            for (int j = 0; j < 4; ++j) {
                size_t row = rbase + j;
#pragma unroll
                for (int ng = 0; ng < 4; ++ng) {
                    int col = col0 + wc * 64 + ng * 16 + l15;
                    Cstr[row * 2048 + col] = (bf16)acc[mg][ng][j];
                }
            }
        }
#pragma unroll
        for (int ng = 0; ng < 4; ++ng) {
            float s = 0;
#pragma unroll
            for (int mg = 0; mg < 8; ++mg)
#pragma unroll
                for (int j = 0; j < 4; ++j) s += acc[mg][ng][j];
            int col = col0 + wc * 64 + ng * 16 + l15;
            atomicAdd(&hm[batch * DD + col], s);
        }
    } else {
        float bi[4];
#pragma unroll
        for (int ng = 0; ng < 4; ++ng) bi[ng] = bias[col0 + wc * 64 + ng * 16 + l15];
#pragma unroll
        for (int mg = 0; mg < 8; ++mg) {
            int rbase = row0 + wr * 128 + (mg >> 2) * 64 + (mg & 3) * 16 + l4 * 4;
#pragma unroll
            for (int j = 0; j < 4; ++j) {
                size_t row = rbase + j;
#pragma unroll
                for (int ng = 0; ng < 4; ++ng) {
                    int col = col0 + wc * 64 + ng * 16 + l15;
                    Cstr[row * 2048 + col] =
                        (bf16)(acc[mg][ng][j] + bi[ng] + (float)residb[row * 1024 + col]);
                }
            }
        }
    }
}

// ---- impedance MLP ----
__global__ __launch_bounds__(1024) void imp_k(const float* __restrict__ hm,
                                              const float* __restrict__ W_pol,
                                              const float* __restrict__ b_pol,
                                              const float* __restrict__ W_imp1,
                                              const float* __restrict__ b_imp1,
                                              const float* __restrict__ W_imp2,
                                              const float* __restrict__ b_imp2,
                                              float* __restrict__ imp_out,
                                              float* __restrict__ coeff) {
    __shared__ float pm_s[32][32];
    int tid = threadIdx.x;
    int bh = tid >> 5, p = tid & 31;
    int b = bh >> 3, h = bh & 7;
    float a = b_pol[h * 32 + p];
    for (int d = 0; d < 128; ++d)
        a += hm[b * DD + h * 128 + d] * (1.0f / SS) * W_pol[(h * 128 + d) * 32 + p];
    float pv = tanhf(a);
    pm_s[bh][p] = pv;
    __syncthreads();
    float ss = 0;
    for (int q = 0; q < 32; ++q) ss += pm_s[bh][q] * pm_s[bh][q];
    float pmv = pv / fmaxf(sqrtf(ss), 1e-12f);
    __syncthreads();
    pm_s[bh][p] = pmv;
    __syncthreads();
    if (tid < 256) {
        int b2 = tid >> 6, h2 = (tid >> 3) & 7, g = tid & 7;
        float dp = 0;
        for (int q = 0; q < 32; ++q) dp += pm_s[b2 * 8 + h2][q] * pm_s[b2 * 8 + g][q];
        float a2 = 0;
        for (int kk = 0; kk < 16; ++kk) {
            float zin = dp * W_imp1[kk] + b_imp1[kk];
            float zg = 0.5f * zin * (1.0f + erff(zin * 0.70710678118654752f));
            a2 += zg * W_imp2[kk];
        }
        float spin = a2 + b_imp2[0];
        float impv = (spin > 20.0f) ? spin : log1pf(expf(spin));
        if (h2 == g) impv = 0.0f;
        imp_out[tid] = impv;
        coeff[tid] = (h2 == g) ? 0.0f : 0.1f / (1.0f + impv);
    }
}

// ---- head mixing: heads (first half of row slot) -> merged (second half) ----
__global__ __launch_bounds__(256) void mix_k(const char* __restrict__ slots,
                                             const float* __restrict__ coeff,
                                             char* __restrict__ slots_w) {
    __shared__ float cf[64];
    int tid = threadIdx.x;
    size_t r0 = (size_t)blockIdx.x * 4;
    int b = (int)(r0 >> 13);
    if (tid < 64) cf[tid] = coeff[b * 64 + tid];
    __syncthreads();
    int lr = tid >> 6;
    int d2 = tid & 63;
    size_t r = r0 + lr;
    int s = (int)(r & (SS - 1));
    float cs = (float)(s + 1) * (1.0f / SS);
    const bf16* hrow = (const bf16*)(slots + r * 4096);
    bf16* mrow = (bf16*)(slots_w + r * 4096 + 2048);
    float v0[8], v1[8];
#pragma unroll
    for (int g = 0; g < 8; ++g) {
        bf16x2 v = *(const bf16x2*)&hrow[g * 128 + d2 * 2];
        v0[g] = (float)v[0]; v1[g] = (float)v[1];
    }
#pragma unroll
    for (int h = 0; h < 8; ++h) {
        float a0 = 0, a1 = 0;
#pragma unroll
        for (int g = 0; g < 8; ++g) {
            float c = cf[h * 8 + g];
            a0 += c * v0[g]; a1 += c * v1[g];
        }
        bf16x2 o;
        o[0] = (bf16)(v0[h] + cs * a0);
        o[1] = (bf16)(v1[h] + cs * a1);
        *(bf16x2*)&mrow[h * 128 + d2 * 2] = o;
    }
}

// ---- LayerNorm: read bf16 z from first 2KB of row slot, write fp32 y over slot ----
__global__ __launch_bounds__(256) void ln_k(char* __restrict__ slots,
                                            const float* __restrict__ gamma,
                                            const float* __restrict__ beta) {
    size_t r = blockIdx.x;
    int tid = threadIdx.x;
    const bf16* zrow = (const bf16*)(slots + r * 4096);
    float* yrow = (float*)(slots + r * 4096);
    int e0 = tid * 4;
    bf16x4 zv = *(const bf16x4*)&zrow[e0];
    float vx = (float)zv[0], vy = (float)zv[1], vz = (float)zv[2], vw = (float)zv[3];
    float sum = vx + vy + vz + vw;
    float sq  = vx * vx + vy * vy + vz * vz + vw * vw;
    for (int off = 32; off > 0; off >>= 1) {
        sum += __shfl_down(sum, off);
        sq  += __shfl_down(sq, off);
    }
    __shared__ float red[8];
    int lane = tid & 63, wv = tid >> 6;
    if (lane == 0) { red[wv] = sum; red[4 + wv] = sq; }
    __syncthreads();
    float tot = red[0] + red[1] + red[2] + red[3];
    float tsq = red[4] + red[5] + red[6] + red[7];
    float mu  = tot * (1.0f / DD);
    float var = tsq * (1.0f / DD) - mu * mu;
    float rs  = rsqrtf(var + 1e-5f);
    float4 g4 = *(const float4*)&gamma[e0];
    float4 b4 = *(const float4*)&beta[e0];
    float4 o;
    o.x = (vx - mu) * rs * g4.x + b4.x;
    o.y = (vy - mu) * rs * g4.y + b4.y;
    o.z = (vz - mu) * rs * g4.z + b4.z;
    o.w = (vw - mu) * rs * g4.w + b4.w;
    *(float4*)&yrow[e0] = o;
}

extern "C" void kernel_launch(void* const* d_in, const int* in_sizes, int n_in,
                              void* d_out, int out_size, void* d_ws, size_t ws_size,
                              hipStream_t stream) {
    const float* x      = (const float*)d_in[0];
    const float* W_proj = (const float*)d_in[1];
    const float* freqs  = (const float*)d_in[2];
    const float* W_pol  = (const float*)d_in[3];
    const float* b_pol  = (const float*)d_in[4];
    const float* W_imp1 = (const float*)d_in[5];
    const float* b_imp1 = (const float*)d_in[6];
    const float* W_imp2 = (const float*)d_in[7];
    const float* b_imp2 = (const float*)d_in[8];
    const float* W_out  = (const float*)d_in[9];
    const float* b_out  = (const float*)d_in[10];
    const float* gamma  = (const float*)d_in[11];
    const float* beta   = (const float*)d_in[12];

    char* ws = (char*)d_ws;
    bf16* xb     = (bf16*)ws;                                  // 64MB
    bf16* WbT1   = (bf16*)(ws + ((size_t)64 << 20));           // 2MB
    bf16* WoT    = (bf16*)(ws + ((size_t)66 << 20));           // 2MB
    float* hm    = (float*)(ws + ((size_t)68 << 20));          // 16KB
    float* coeff = (float*)(ws + ((size_t)68 << 20) + 16384);  // 1KB

    char* slots = (char*)d_out;                      // 128MB of 4KB row slots
    float* imp_out = (float*)d_out + (size_t)MM * DD;

    prep_all<<<MM + 4096, 256, 0, stream>>>(x, xb, W_proj, freqs, W_out,
                                            WbT1, WoT, hm);

    // GEMM1: heads -> first half of row slots (+ hm column sums)
    gemm256<0><<<512, 512, 0, stream>>>(xb, 1024, WbT1, (bf16*)slots,
                                        nullptr, nullptr, hm);

    imp_k<<<1, 1024, 0, stream>>>(hm, W_pol, b_pol, W_imp1, b_imp1, W_imp2, b_imp2,
                                  imp_out, coeff);

    mix_k<<<MM / 4, 256, 0, stream>>>(slots, coeff, slots);    // heads -> merged

    // GEMM2: A = merged (second half, stride 2048); z -> first half of slots
    gemm256<1><<<512, 512, 0, stream>>>((const bf16*)slots + 1024, 2048, WoT,
                                        (bf16*)slots, xb, b_out, nullptr);

    ln_k<<<MM, 256, 0, stream>>>(slots, gamma, beta);
}